// Round 15
// baseline (374.382 us; speedup 1.0000x reference)
//
#include <hip/hip_runtime.h>
#include <hip/hip_bf16.h>

typedef unsigned short u16;
typedef short bf16x8 __attribute__((ext_vector_type(8)));
typedef float f32x4 __attribute__((ext_vector_type(4)));

#define CC 512

// s_waitcnt imm encoding: vmcnt[3:0]|[15:14], expcnt[6:4]=7 (no wait),
// lgkmcnt[11:8]=0xF (no wait)
constexpr int vmimm(int n) {
    return (n & 0xF) | ((n >> 4) << 14) | (0x7 << 4) | (0xF << 8);
}

__device__ __forceinline__ float gelu_tanh(float x) {
    float x3 = x * x * x;
    float z  = 0.7978845608028654f * (x + 0.044715f * x3);
    float e  = __expf(2.0f * z);
    float th = 1.0f - 2.0f / (e + 1.0f);
    return 0.5f * x * (1.0f + th);
}

__device__ __forceinline__ u16 f2bf(float f) {
    union { float f; unsigned u; } v; v.f = f;
    unsigned r = v.u + 0x7fff + ((v.u >> 16) & 1);
    return (u16)(r >> 16);
}
__device__ __forceinline__ float bf2f(u16 h) {
    union { unsigned u; float f; } v; v.u = ((unsigned)h) << 16; return v.f;
}

// ---------------- conv0 pass 1: per-channel partial stats (NO store) -------
__global__ __launch_bounds__(256) void conv0_stats(
    const float* __restrict__ x, const float* __restrict__ w0,
    float* __restrict__ part) {
    const int t0 = blockIdx.x * 64, b = blockIdx.y;
    __shared__ float xs[64 * 5 + 16];
    __shared__ float w0t[10 * 512];
    __shared__ float redS[4][512], redQ[4][512];
    for (int i = threadIdx.x; i < 64 * 5 + 5; i += 256) {
        int gi = t0 * 5 + i;
        xs[i] = (gi < 40000) ? x[b * 40000 + gi] : 0.0f;
    }
    for (int i = threadIdx.x; i < 5120; i += 256) {
        int c = i / 10, j = i - c * 10;
        w0t[j * 512 + c] = w0[i];
    }
    __syncthreads();
    const int lane = threadIdx.x & 63, wv = threadIdx.x >> 6;
    float wr[8][10];
#pragma unroll
    for (int q = 0; q < 8; ++q)
#pragma unroll
        for (int j = 0; j < 10; ++j) wr[q][j] = w0t[j * 512 + lane + 64 * q];
    float sacc[8] = {}, qacc[8] = {};
#pragma unroll
    for (int u = 0; u < 16; ++u) {
        const int tt = wv * 16 + u;
        const int t  = t0 + tt;
        float xv[10];
#pragma unroll
        for (int j = 0; j < 10; ++j) xv[j] = xs[tt * 5 + j];
#pragma unroll
        for (int q = 0; q < 8; ++q) {
            float a = 0.0f;
#pragma unroll
            for (int j = 0; j < 10; ++j) a = fmaf(wr[q][j], xv[j], a);
            if (t < 7999) {
                const float ar = bf2f(f2bf(a));
                sacc[q] += ar; qacc[q] += ar * ar;
            }
        }
    }
#pragma unroll
    for (int q = 0; q < 8; ++q) {
        redS[wv][lane + 64 * q] = sacc[q];
        redQ[wv][lane + 64 * q] = qacc[q];
    }
    __syncthreads();
    float* pp = part + (((size_t)blockIdx.x * 8 + b) * 512) * 2;
#pragma unroll
    for (int half = 0; half < 2; ++half) {
        const int c = half * 256 + threadIdx.x;
        const float s = redS[0][c] + redS[1][c] + redS[2][c] + redS[3][c];
        const float q = redQ[0][c] + redQ[1][c] + redQ[2][c] + redQ[3][c];
        pp[c * 2] = s; pp[c * 2 + 1] = q;
    }
}

// reduce partials (125 per row) -> per-(b,c) affine A,B
__global__ __launch_bounds__(256) void stats_finalizeAB(
    const float* __restrict__ part, const float* __restrict__ gsc,
    const float* __restrict__ gbi, float* __restrict__ Af, float* __restrict__ Bf) {
    const int r4 = threadIdx.x & 63, kg = threadIdx.x >> 6;
    const int row = blockIdx.x * 64 + r4;            // b*512 + c
    float s = 0.0f, q = 0.0f;
    for (int k = kg; k < 125; k += 4) {
        const float2 v = *(const float2*)(part + ((size_t)k * 4096 + row) * 2);
        s += v.x; q += v.y;
    }
    __shared__ float rs[4][64], rq[4][64];
    rs[kg][r4] = s; rq[kg][r4] = q;
    __syncthreads();
    if (kg == 0) {
        s = rs[0][r4] + rs[1][r4] + rs[2][r4] + rs[3][r4];
        q = rq[0][r4] + rq[1][r4] + rq[2][r4] + rq[3][r4];
        float mean = s / 7999.0f;
        float var  = fmaxf(q / 7999.0f - mean * mean, 0.0f);
        float rstd = rsqrtf(var + 1e-5f);
        const int c = row & (CC - 1);
        float A = rstd * gsc[c];
        Af[row] = A;
        Bf[row] = gbi[c] - mean * A;
    }
}

// ---------------- conv0 pass 2: recompute + norm + gelu -> actG ------------
__global__ __launch_bounds__(256) void conv0_norm(
    const float* __restrict__ x, const float* __restrict__ w0,
    const float* __restrict__ Af, const float* __restrict__ Bf,
    u16* __restrict__ actG) {
    const int t0 = blockIdx.x * 64, b = blockIdx.y;
    __shared__ float xs[64 * 5 + 16];
    __shared__ float w0t[10 * 512];
    for (int i = threadIdx.x; i < 64 * 5 + 5; i += 256) {
        int gi = t0 * 5 + i;
        xs[i] = (gi < 40000) ? x[b * 40000 + gi] : 0.0f;
    }
    for (int i = threadIdx.x; i < 5120; i += 256) {
        int c = i / 10, j = i - c * 10;
        w0t[j * 512 + c] = w0[i];
    }
    __syncthreads();
    const int lane = threadIdx.x & 63, wv = threadIdx.x >> 6;
    float wr[8][10];
    float Ar[8], Br[8];
#pragma unroll
    for (int q = 0; q < 8; ++q) {
        const int c = lane + 64 * q;
#pragma unroll
        for (int j = 0; j < 10; ++j) wr[q][j] = w0t[j * 512 + c];
        Ar[q] = Af[b * 512 + c];
        Br[q] = Bf[b * 512 + c];
    }
    u16* ob = actG + ((size_t)b * 8320 + t0 + wv * 16) * 512 + lane;
#pragma unroll
    for (int u = 0; u < 16; ++u) {
        const int tt = wv * 16 + u;
        const int t  = t0 + tt;
        float xv[10];
#pragma unroll
        for (int j = 0; j < 10; ++j) xv[j] = xs[tt * 5 + j];
#pragma unroll
        for (int q = 0; q < 8; ++q) {
            float a = 0.0f;
#pragma unroll
            for (int j = 0; j < 10; ++j) a = fmaf(wr[q][j], xv[j], a);
            u16 outv = 0;
            if (t < 7999) {
                const float ar = bf2f(f2bf(a));
                outv = f2bf(gelu_tanh(fmaf(ar, Ar[q], Br[q])));
            }
            ob[(size_t)u * 512 + 64 * q] = outv;
        }
    }
}

// ---------------- weight pre-transform (hi only), batched ------------------
// Layout: [cob(4 x 128co)][cit(16)][co(128)][WROW=32K+8]
template <int K, int NL>
struct WtBatch { const float* src[NL]; u16* dst[NL]; };

template <int K, int NL>
__global__ __launch_bounds__(256) void wt_transform(WtBatch<K, NL> a) {
    constexpr int WROW = 32 * K + 8;
    const int cit = blockIdx.x, cob = blockIdx.y, l = blockIdx.z;
    const float* w = a.src[l];
    u16* dst = a.dst[l] + ((size_t)(cob * 16 + cit)) * 128 * WROW;
    for (int idx = threadIdx.x; idx < 128 * WROW; idx += 256) {
        const int co = idx / WROW, e = idx - co * WROW;
        u16 hi = 0;
        if (e < 32 * K) {
            const int j = e >> 5, ci = e & 31;
            hi = f2bf(w[((size_t)(cob * 128 + co) * 512 + cit * 32 + ci) * K + j]);
        }
        dst[idx] = hi;
    }
}

// ---------------- MFMA conv (512->512, k=K, stride 2) + gelu ---------------
// Block 128co x TT t, 4 waves (2co x 2t).
// X: LDS double-buffered (gload_lds), depth-2 counted-vmcnt pipeline.
// W: DIRECT global->register (L1/L2-resident plane), rolling refill:
//    per tap j: MFMA with wr[j] (loaded last cit), then refill wr[j] from
//    plane(cit+1) -> full-body latency cover; compiler auto-waits the dep.
// Per cit: ds_read X frags (12) -> lgkmcnt(0) -> s_barrier -> stage X(cit+2)
//   -> taps {MFMA, refill} -> vmcnt(NIX + 2*WREF) -> s_barrier.
// Wait math: target = X(cit+1) landed; issued after it = refills(cit-1) WREF
//   + X-stage(cit) NIX + refills(cit) WREF.
// VGPR NOTE: never cap below the live set via launch_bounds (R6/R10 spills).
template <int K, int TT>
__global__ __launch_bounds__(256, 2) void conv_mfma(
    const u16* __restrict__ act, int capIn,
    const u16* __restrict__ wt,
    u16* __restrict__ outAct, int capOut, int tbShift) {
    constexpr int WROW = 32 * K + 8;
    constexpr int PLANE = 128 * WROW;        // u16 per (cob,cit) W plane
    constexpr int XH   = TT + 8;             // x-pair rows (128 B each)
    constexpr int TF   = TT / 32;
    constexpr int TXC  = XH * 8;             // 16B chunks per X buffer
    constexpr int CPX  = TXC / 4;            // chunks per wave
    constexpr int NIX  = (CPX + 63) / 64;    // X stage instrs per wave
    constexpr int XLAST = CPX - (NIX - 1) * 64;
    constexpr int WREF = K * 4;              // W refill loads per cit
    constexpr int VM_MAIN = NIX + 2 * WREF;

    __shared__ __align__(16) u16 Xs[2][XH * 64];

    const int tid  = threadIdx.x;
    const int lane = tid & 63;
    const int wv   = tid >> 6;
    const int wco  = wv >> 1, wtt = wv & 1;
    const int l15  = lane & 15, l16 = lane >> 4;

    const int flat = blockIdx.x;
    const int xcd  = flat & 7, cob = (flat >> 3) & 3;
    const int G    = xcd + (flat >> 5) * 8;
    const int t_b  = G & ((1 << tbShift) - 1);
    const int b    = G >> tbShift;
    const int t0   = t_b * TT;
    const int x0   = t0 * 2;

    const char* abase = (const char*)(act + (size_t)b * capIn * 512);
    const u16*  wbase = wt + (size_t)cob * (16 * PLANE);

    // ---- X staging pointers: set A stages even cits (buf0), B odd ----
    const char* xsA[NIX]; const char* xsB[NIX]; int xdst[NIX];
#pragma unroll
    for (int i = 0; i < NIX; ++i) {
        const int c  = wv * CPX + i * 64 + lane;
        const int xh = c >> 3;
        const int li = ((c & 7) * 16) ^ ((xh & 7) << 4);
        const int xx = min(x0 + 2 * xh + (li >> 6), capIn - 1);
        xsA[i] = abase + (size_t)xx * 1024 + (li & 63);
        xsB[i] = xsA[i] + 64;                       // +1 cit
        xdst[i] = (wv * CPX + i * 64) * 16;         // wave-uniform LDS base
    }

    auto stageX = [&](const char* (&xs)[NIX], u16* xb) {
#pragma unroll
        for (int i = 0; i < NIX; ++i)
            if (i < NIX - 1 || lane < XLAST)
                __builtin_amdgcn_global_load_lds(
                    (const __attribute__((address_space(1))) void*)xs[i],
                    (__attribute__((address_space(3))) void*)((char*)xb + xdst[i]),
                    16, 0, 0);
#pragma unroll
        for (int i = 0; i < NIX; ++i) xs[i] += 128;          // +2 cits
    };

    // cit-invariant fragment offsets
    int xoff[K][TF];        // bytes into X LDS buffer
    int woffB[K][4];        // bytes into W plane (global)
#pragma unroll
    for (int j = 0; j < K; ++j) {
#pragma unroll
        for (int tf = 0; tf < TF; ++tf) {
            const int tl = wtt * (TT / 2) + tf * 16 + l15;
            const int xl = 2 * tl + j;
            const int xh = xl >> 1, p = xl & 1;
            xoff[j][tf] = xh * 128 + ((p * 64 + l16 * 16) ^ ((xh & 7) << 4));
        }
#pragma unroll
        for (int cf = 0; cf < 4; ++cf)
            woffB[j][cf] = ((wco * 64 + cf * 16 + l15) * WROW + j * 32 + l16 * 8) * 2;
    }

    f32x4 acc[4][TF] = {};
    bf16x8 wr[K][4];

    // prologue: X(0)->buf0, X(1)->buf1, W(0)->regs; full drain via barrier
    stageX(xsA, &Xs[0][0]);
    stageX(xsB, &Xs[1][0]);
    const char* wNext = (const char*)wbase;
#pragma unroll
    for (int j = 0; j < K; ++j)
#pragma unroll
        for (int cf = 0; cf < 4; ++cf)
            wr[j][cf] = *(const bf16x8*)(wNext + woffB[j][cf]);
    wNext += PLANE * 2;                      // plane 1 (bytes)
    __syncthreads();

    auto body = [&](int cit, u16* xb, const char* (&xset)[NIX]) {
        bf16x8 xr[K][TF];
#pragma unroll
        for (int j = 0; j < K; ++j)
#pragma unroll
            for (int tf = 0; tf < TF; ++tf)
                xr[j][tf] = *(const bf16x8*)((const char*)xb + xoff[j][tf]);
        asm volatile("s_waitcnt lgkmcnt(0)" ::: "memory");   // X reads done
        __builtin_amdgcn_s_barrier();                        // all waves done
        if (cit < 14) stageX(xset, xb);                      // X(cit+2)
#pragma unroll
        for (int j = 0; j < K; ++j) {
#pragma unroll
            for (int cf = 0; cf < 4; ++cf)
#pragma unroll
                for (int tf = 0; tf < TF; ++tf)
                    acc[cf][tf] = __builtin_amdgcn_mfma_f32_16x16x32_bf16(
                        wr[j][cf], xr[j][tf], acc[cf][tf], 0, 0, 0);
            if (cit < 15) {
#pragma unroll
                for (int cf = 0; cf < 4; ++cf)               // refill for cit+1
                    wr[j][cf] = *(const bf16x8*)(wNext + woffB[j][cf]);
            }
        }
        wNext += PLANE * 2;
        if (cit < 14) {
            __builtin_amdgcn_s_waitcnt(vmimm(VM_MAIN));      // X(cit+1) landed
            __builtin_amdgcn_s_barrier();
        } else if (cit == 14) {
            __builtin_amdgcn_s_waitcnt(vmimm(0));
            __builtin_amdgcn_s_barrier();
        }
    };

#pragma unroll 1
    for (int c2 = 0; c2 < 16; c2 += 2) {
        body(c2,     &Xs[0][0], xsA);
        body(c2 + 1, &Xs[1][0], xsB);
    }

    // epilogue: gelu + bf16 transposed store [b][t][512]
    u16* ob = outAct + (size_t)b * capOut * 512;
#pragma unroll
    for (int cf = 0; cf < 4; ++cf) {
#pragma unroll
        for (int tf = 0; tf < TF; ++tf) {
            const int tG  = t0 + wtt * (TT / 2) + tf * 16 + l15;
            const int coG = cob * 128 + wco * 64 + cf * 16 + l16 * 4;
            union { u16 s[4]; uint2 v; } pk;
#pragma unroll
            for (int r = 0; r < 4; ++r)
                pk.s[r] = f2bf(gelu_tanh(acc[cf][tf][r]));
            *(uint2*)(ob + (size_t)tG * 512 + coG) = pk.v;
        }
    }
}

// ---------------- time-mean + proj + relu ----------------------------------
__global__ __launch_bounds__(512) void feat_proj_kernel(
    const u16* __restrict__ act, int cap,
    const float* __restrict__ pw, const float* __restrict__ pb,
    float* __restrict__ pfeat) {
    const int b = blockIdx.x;
    __shared__ float fs[8][512];
    __shared__ float feat[CC];
    const int c8 = (threadIdx.x & 63) * 8;
    const int tg = threadIdx.x >> 6;
    float s[8] = {};
    for (int t = tg; t < 124; t += 8) {
        union { u16 u[8]; uint4 v; } in;
        in.v = *(const uint4*)(act + ((size_t)b * cap + t) * 512 + c8);
#pragma unroll
        for (int e = 0; e < 8; ++e) s[e] += bf2f(in.u[e]);
    }
#pragma unroll
    for (int e = 0; e < 8; ++e) fs[tg][c8 + e] = s[e];
    __syncthreads();
    {
        const int c = threadIdx.x;
        if (c < 512) {
            float acc = 0.0f;
#pragma unroll
            for (int g = 0; g < 8; ++g) acc += fs[g][c];
            feat[c] = acc * (1.0f / 124.0f);
        }
    }
    __syncthreads();
    if (threadIdx.x < 256) {
        const int j = threadIdx.x;
        const float* wr = pw + (size_t)j * CC;
        float acc = pb[j];
        for (int cc = 0; cc < CC; ++cc) acc = fmaf(feat[cc], wr[cc], acc);
        pfeat[b * 256 + j] = fmaxf(acc, 0.0f);
    }
}

// ---------------- per-sample classifier MLP --------------------------------
__global__ __launch_bounds__(128) void cls_kernel(
    const float* __restrict__ pfeat, const int* __restrict__ wid,
    const float* __restrict__ w1, const float* __restrict__ b1,
    const float* __restrict__ w2, const float* __restrict__ b2,
    float* __restrict__ out) {
    const int b = blockIdx.x;
    const int id = wid[b];
    __shared__ float pf[256], h1[128];
    for (int d = threadIdx.x; d < 256; d += 128) pf[d] = pfeat[b * 256 + d];
    __syncthreads();
    {
        const int hh = threadIdx.x;
        const float* w1p = w1 + (size_t)id * 256 * 128;
        float s = b1[id * 128 + hh];
        for (int d = 0; d < 256; ++d) s = fmaf(pf[d], w1p[d * 128 + hh], s);
        h1[hh] = fmaxf(s, 0.0f);
    }
    __syncthreads();
    if (threadIdx.x < 5) {
        const float* w2p = w2 + (size_t)id * 128 * 5;
        float s = b2[id * 5 + threadIdx.x];
        for (int hh = 0; hh < 128; ++hh) s = fmaf(h1[hh], w2p[hh * 5 + threadIdx.x], s);
        out[b * 5 + threadIdx.x] = s;
    }
}

// ---------------------------------------------------------------------------
extern "C" void kernel_launch(void* const* d_in, const int* in_sizes, int n_in,
                              void* d_out, int out_size, void* d_ws, size_t ws_size,
                              hipStream_t stream) {
    const float* x   = (const float*)d_in[0];
    const int*   wid = (const int*)d_in[1];
    const float* gsc = (const float*)d_in[2];
    const float* gbi = (const float*)d_in[3];
    const float* pw  = (const float*)d_in[4];
    const float* pb  = (const float*)d_in[5];
    const float* w1  = (const float*)d_in[6];
    const float* b1  = (const float*)d_in[7];
    const float* w2  = (const float*)d_in[8];
    const float* b2  = (const float*)d_in[9];
    const float* cw[7];
    for (int i = 0; i < 7; ++i) cw[i] = (const float*)d_in[10 + i];

    // ---- workspace layout ----
    char* ws = (char*)d_ws;
    const size_t SZ_ACTG = (size_t)8 * 8320 * 512 * 2;
    const size_t SZ_P    = (size_t)8 * 4224 * 512 * 2;
    const size_t SZ_Q    = (size_t)8 * 2176 * 512 * 2;
    u16* actG = (u16*)ws;
    u16* bufP = (u16*)(ws + SZ_ACTG);
    u16* bufQ = (u16*)(ws + SZ_ACTG + SZ_P);
    size_t off = SZ_ACTG + SZ_P + SZ_Q;
    u16* wtbuf[7];
    for (int i = 1; i <= 4; ++i) { wtbuf[i] = (u16*)(ws + off); off += (size_t)4 * 16 * 128 * 104 * 2; }
    for (int i = 5; i <= 6; ++i) { wtbuf[i] = (u16*)(ws + off); off += (size_t)4 * 16 * 128 * 72 * 2; }
    off = (off + 255) & ~(size_t)255;
    float* statsPart = (float*)(ws + off); off += (size_t)125 * 8 * 512 * 2 * 4;
    float* Af        = (float*)(ws + off); off += 4096 * 4;
    float* Bf        = (float*)(ws + off); off += 4096 * 4;
    float* pfeat     = (float*)(ws + off); off += 8 * 256 * 4;

    // ---- conv0: stats pass (no store) -> affine -> recompute+norm+store ---
    conv0_stats<<<dim3(125, 8), 256, 0, stream>>>(x, cw[0], statsPart);
    stats_finalizeAB<<<dim3(64), 256, 0, stream>>>(statsPart, gsc, gbi, Af, Bf);
    conv0_norm<<<dim3(125, 8), 256, 0, stream>>>(x, cw[0], Af, Bf, actG);

    // ---- weight pre-transforms (2 launches) ----
    {
        WtBatch<3, 4> a;
        for (int i = 0; i < 4; ++i) { a.src[i] = cw[1 + i]; a.dst[i] = wtbuf[1 + i]; }
        wt_transform<3, 4><<<dim3(16, 4, 4), 256, 0, stream>>>(a);
        WtBatch<2, 2> c;
        for (int i = 0; i < 2; ++i) { c.src[i] = cw[5 + i]; c.dst[i] = wtbuf[5 + i]; }
        wt_transform<2, 2><<<dim3(16, 4, 2), 256, 0, stream>>>(c);
    }

    // ---- conv chain: 1-D grids, blocks = nTb*4*8, tbShift = log2(nTb) ----
    conv_mfma<3, 128><<<dim3(32 * 32), 256, 0, stream>>>(actG, 8320, wtbuf[1], bufP, 4224, 5);
    conv_mfma<3, 128><<<dim3(16 * 32), 256, 0, stream>>>(bufP, 4224, wtbuf[2], bufQ, 2176, 4);
    conv_mfma<3,  64><<<dim3(16 * 32), 256, 0, stream>>>(bufQ, 2176, wtbuf[3], bufP, 4224, 4);
    conv_mfma<3,  64><<<dim3( 8 * 32), 256, 0, stream>>>(bufP, 4224, wtbuf[4], bufQ, 2176, 3);
    conv_mfma<2,  64><<<dim3( 4 * 32), 256, 0, stream>>>(bufQ, 2176, wtbuf[5], bufP, 4224, 2);
    conv_mfma<2,  64><<<dim3( 2 * 32), 256, 0, stream>>>(bufP, 4224, wtbuf[6], bufQ, 2176, 1);

    // ---- tail ----
    feat_proj_kernel<<<dim3(8), 512, 0, stream>>>(bufQ, 2176, pw, pb, pfeat);
    cls_kernel<<<dim3(8), 128, 0, stream>>>(pfeat, wid, w1, b1, w2, b2, (float*)d_out);
}

// Round 16
// 310.837 us; speedup vs baseline: 1.2044x; 1.2044x over previous
//
#include <hip/hip_runtime.h>
#include <hip/hip_bf16.h>

typedef unsigned short u16;
typedef short bf16x8 __attribute__((ext_vector_type(8)));
typedef float f32x4 __attribute__((ext_vector_type(4)));

#define CC 512

// s_waitcnt imm encoding: vmcnt[3:0]|[15:14], expcnt[6:4]=7 (no wait),
// lgkmcnt[11:8]=0xF (no wait)
constexpr int vmimm(int n) {
    return (n & 0xF) | ((n >> 4) << 14) | (0x7 << 4) | (0xF << 8);
}

__device__ __forceinline__ float gelu_tanh(float x) {
    float x3 = x * x * x;
    float z  = 0.7978845608028654f * (x + 0.044715f * x3);
    float e  = __expf(2.0f * z);
    float th = 1.0f - 2.0f / (e + 1.0f);
    return 0.5f * x * (1.0f + th);
}

__device__ __forceinline__ u16 f2bf(float f) {
    union { float f; unsigned u; } v; v.f = f;
    unsigned r = v.u + 0x7fff + ((v.u >> 16) & 1);
    return (u16)(r >> 16);
}
__device__ __forceinline__ float bf2f(u16 h) {
    union { unsigned u; float f; } v; v.u = ((unsigned)h) << 16; return v.f;
}

// ---------------- conv0 pass 1: per-channel partial stats (NO store) -------
__global__ __launch_bounds__(256) void conv0_stats(
    const float* __restrict__ x, const float* __restrict__ w0,
    float* __restrict__ part) {
    const int t0 = blockIdx.x * 64, b = blockIdx.y;
    __shared__ float xs[64 * 5 + 16];
    __shared__ float w0t[10 * 512];
    __shared__ float redS[4][512], redQ[4][512];
    for (int i = threadIdx.x; i < 64 * 5 + 5; i += 256) {
        int gi = t0 * 5 + i;
        xs[i] = (gi < 40000) ? x[b * 40000 + gi] : 0.0f;
    }
    for (int i = threadIdx.x; i < 5120; i += 256) {
        int c = i / 10, j = i - c * 10;
        w0t[j * 512 + c] = w0[i];
    }
    __syncthreads();
    const int lane = threadIdx.x & 63, wv = threadIdx.x >> 6;
    float wr[8][10];
#pragma unroll
    for (int q = 0; q < 8; ++q)
#pragma unroll
        for (int j = 0; j < 10; ++j) wr[q][j] = w0t[j * 512 + lane + 64 * q];
    float sacc[8] = {}, qacc[8] = {};
#pragma unroll
    for (int u = 0; u < 16; ++u) {
        const int tt = wv * 16 + u;
        const int t  = t0 + tt;
        float xv[10];
#pragma unroll
        for (int j = 0; j < 10; ++j) xv[j] = xs[tt * 5 + j];
#pragma unroll
        for (int q = 0; q < 8; ++q) {
            float a = 0.0f;
#pragma unroll
            for (int j = 0; j < 10; ++j) a = fmaf(wr[q][j], xv[j], a);
            if (t < 7999) {
                const float ar = bf2f(f2bf(a));
                sacc[q] += ar; qacc[q] += ar * ar;
            }
        }
    }
#pragma unroll
    for (int q = 0; q < 8; ++q) {
        redS[wv][lane + 64 * q] = sacc[q];
        redQ[wv][lane + 64 * q] = qacc[q];
    }
    __syncthreads();
    float* pp = part + (((size_t)blockIdx.x * 8 + b) * 512) * 2;
#pragma unroll
    for (int half = 0; half < 2; ++half) {
        const int c = half * 256 + threadIdx.x;
        const float s = redS[0][c] + redS[1][c] + redS[2][c] + redS[3][c];
        const float q = redQ[0][c] + redQ[1][c] + redQ[2][c] + redQ[3][c];
        pp[c * 2] = s; pp[c * 2 + 1] = q;
    }
}

// reduce partials (125 per row) -> per-(b,c) affine A,B
__global__ __launch_bounds__(256) void stats_finalizeAB(
    const float* __restrict__ part, const float* __restrict__ gsc,
    const float* __restrict__ gbi, float* __restrict__ Af, float* __restrict__ Bf) {
    const int r4 = threadIdx.x & 63, kg = threadIdx.x >> 6;
    const int row = blockIdx.x * 64 + r4;            // b*512 + c
    float s = 0.0f, q = 0.0f;
    for (int k = kg; k < 125; k += 4) {
        const float2 v = *(const float2*)(part + ((size_t)k * 4096 + row) * 2);
        s += v.x; q += v.y;
    }
    __shared__ float rs[4][64], rq[4][64];
    rs[kg][r4] = s; rq[kg][r4] = q;
    __syncthreads();
    if (kg == 0) {
        s = rs[0][r4] + rs[1][r4] + rs[2][r4] + rs[3][r4];
        q = rq[0][r4] + rq[1][r4] + rq[2][r4] + rq[3][r4];
        float mean = s / 7999.0f;
        float var  = fmaxf(q / 7999.0f - mean * mean, 0.0f);
        float rstd = rsqrtf(var + 1e-5f);
        const int c = row & (CC - 1);
        float A = rstd * gsc[c];
        Af[row] = A;
        Bf[row] = gbi[c] - mean * A;
    }
}

// ---------------- conv0 pass 2: recompute + norm + gelu -> actG ------------
__global__ __launch_bounds__(256) void conv0_norm(
    const float* __restrict__ x, const float* __restrict__ w0,
    const float* __restrict__ Af, const float* __restrict__ Bf,
    u16* __restrict__ actG) {
    const int t0 = blockIdx.x * 64, b = blockIdx.y;
    __shared__ float xs[64 * 5 + 16];
    __shared__ float w0t[10 * 512];
    for (int i = threadIdx.x; i < 64 * 5 + 5; i += 256) {
        int gi = t0 * 5 + i;
        xs[i] = (gi < 40000) ? x[b * 40000 + gi] : 0.0f;
    }
    for (int i = threadIdx.x; i < 5120; i += 256) {
        int c = i / 10, j = i - c * 10;
        w0t[j * 512 + c] = w0[i];
    }
    __syncthreads();
    const int lane = threadIdx.x & 63, wv = threadIdx.x >> 6;
    float wr[8][10];
    float Ar[8], Br[8];
#pragma unroll
    for (int q = 0; q < 8; ++q) {
        const int c = lane + 64 * q;
#pragma unroll
        for (int j = 0; j < 10; ++j) wr[q][j] = w0t[j * 512 + c];
        Ar[q] = Af[b * 512 + c];
        Br[q] = Bf[b * 512 + c];
    }
    u16* ob = actG + ((size_t)b * 8320 + t0 + wv * 16) * 512 + lane;
#pragma unroll
    for (int u = 0; u < 16; ++u) {
        const int tt = wv * 16 + u;
        const int t  = t0 + tt;
        float xv[10];
#pragma unroll
        for (int j = 0; j < 10; ++j) xv[j] = xs[tt * 5 + j];
#pragma unroll
        for (int q = 0; q < 8; ++q) {
            float a = 0.0f;
#pragma unroll
            for (int j = 0; j < 10; ++j) a = fmaf(wr[q][j], xv[j], a);
            u16 outv = 0;
            if (t < 7999) {
                const float ar = bf2f(f2bf(a));
                outv = f2bf(gelu_tanh(fmaf(ar, Ar[q], Br[q])));
            }
            ob[(size_t)u * 512 + 64 * q] = outv;
        }
    }
}

// ---------------- weight pre-transform (hi only), batched ------------------
// Layout: [cob(4 x 128co)][cit(16)][co(128)][WROW=32K+8]
template <int K, int NL>
struct WtBatch { const float* src[NL]; u16* dst[NL]; };

template <int K, int NL>
__global__ __launch_bounds__(256) void wt_transform(WtBatch<K, NL> a) {
    constexpr int WROW = 32 * K + 8;
    const int cit = blockIdx.x, cob = blockIdx.y, l = blockIdx.z;
    const float* w = a.src[l];
    u16* dst = a.dst[l] + ((size_t)(cob * 16 + cit)) * 128 * WROW;
    for (int idx = threadIdx.x; idx < 128 * WROW; idx += 256) {
        const int co = idx / WROW, e = idx - co * WROW;
        u16 hi = 0;
        if (e < 32 * K) {
            const int j = e >> 5, ci = e & 31;
            hi = f2bf(w[((size_t)(cob * 128 + co) * 512 + cit * 32 + ci) * K + j]);
        }
        dst[idx] = hi;
    }
}

// ---------------- MFMA conv (512->512, k=K, stride 2) + gelu ---------------
// Block 128co x TT t, 4 waves (2co x 2t). Depth-2 counted-vmcnt pipeline:
// X double-buffered in LDS, W single-buffered (R14 memory structure).
// R16 body reorder: reads -> MFMA taps 0..K-2 (compiler interleaves counted
// lgkm waits with the reads -> read latency hidden under MFMA) -> lgkm(0) ->
// s_barrier -> stage W(cit+1), X(cit+2) -> MFMA tap K-1 (covers staging) ->
// vmcnt(NIX) -> s_barrier.
// Per-wave staging: contiguous chunk ranges + lane-masked last load so every
// wave issues EXACTLY NIX/NIW loads -> vmcnt(N) exact; W before X -> N=NIX.
// VGPR NOTE: never cap below ~130 via launch_bounds (R6/R10 spill disasters).
template <int K, int TT>
__global__ __launch_bounds__(256, 2) void conv_mfma(
    const u16* __restrict__ act, int capIn,
    const u16* __restrict__ wt,
    u16* __restrict__ outAct, int capOut, int tbShift) {
    constexpr int WROW = 32 * K + 8;
    constexpr int XH   = TT + 8;             // x-pair rows (128 B each)
    constexpr int TF   = TT / 32;
    constexpr int TXC  = XH * 8;             // 16B chunks per X buffer
    constexpr int CPX  = TXC / 4;            // chunks per wave
    constexpr int NIX  = (CPX + 63) / 64;    // load instrs per wave (X)
    constexpr int XLAST = CPX - (NIX - 1) * 64;
    constexpr int TWC  = 128 * WROW / 8;     // 16B chunks in W tile
    constexpr int CPW  = TWC / 4;
    constexpr int NIW  = (CPW + 63) / 64;
    constexpr int WLAST = CPW - (NIW - 1) * 64;

    __shared__ __align__(16) u16 Xs[2][XH * 64];
    __shared__ __align__(16) u16 Ws[128 * WROW];

    const int tid  = threadIdx.x;
    const int lane = tid & 63;
    const int wv   = tid >> 6;
    const int wco  = wv >> 1, wtt = wv & 1;
    const int l15  = lane & 15, l16 = lane >> 4;

    const int flat = blockIdx.x;
    const int xcd  = flat & 7, cob = (flat >> 3) & 3;
    const int G    = xcd + (flat >> 5) * 8;
    const int t_b  = G & ((1 << tbShift) - 1);
    const int b    = G >> tbShift;
    const int t0   = t_b * TT;
    const int x0   = t0 * 2;

    const char* abase = (const char*)(act + (size_t)b * capIn * 512);
    const u16*  wbase = wt + (size_t)cob * (16 * 128 * WROW);

    // ---- staging pointers: set A stages even cits (buf0), B odd (buf1) ----
    const char* xsA[NIX]; const char* xsB[NIX]; int xdst[NIX];
#pragma unroll
    for (int i = 0; i < NIX; ++i) {
        const int c  = wv * CPX + i * 64 + lane;
        const int xh = c >> 3;
        const int li = ((c & 7) * 16) ^ ((xh & 7) << 4);
        const int xx = min(x0 + 2 * xh + (li >> 6), capIn - 1);
        xsA[i] = abase + (size_t)xx * 1024 + (li & 63);
        xsB[i] = xsA[i] + 64;                       // +1 cit
        xdst[i] = (wv * CPX + i * 64) * 16;         // wave-uniform LDS base
    }
    const char* wsrc[NIW]; int wdst[NIW];
#pragma unroll
    for (int i = 0; i < NIW; ++i) {
        wsrc[i] = (const char*)wbase + (size_t)(wv * CPW + i * 64 + lane) * 16;
        wdst[i] = (wv * CPW + i * 64) * 16;
    }

    auto stageX = [&](const char* (&xs)[NIX], u16* xb) {
#pragma unroll
        for (int i = 0; i < NIX; ++i)
            if (i < NIX - 1 || lane < XLAST)
                __builtin_amdgcn_global_load_lds(
                    (const __attribute__((address_space(1))) void*)xs[i],
                    (__attribute__((address_space(3))) void*)((char*)xb + xdst[i]),
                    16, 0, 0);
#pragma unroll
        for (int i = 0; i < NIX; ++i) xs[i] += 128;          // +2 cits
    };
    auto stageW = [&]() {
#pragma unroll
        for (int i = 0; i < NIW; ++i)
            if (i < NIW - 1 || lane < WLAST)
                __builtin_amdgcn_global_load_lds(
                    (const __attribute__((address_space(1))) void*)wsrc[i],
                    (__attribute__((address_space(3))) void*)((char*)&Ws[0] + wdst[i]),
                    16, 0, 0);
#pragma unroll
        for (int i = 0; i < NIW; ++i) wsrc[i] += WROW * 256; // next cit plane
    };

    // cit-invariant fragment offsets (bytes)
    int xoff[K][TF];
    int woff[K][4];
#pragma unroll
    for (int j = 0; j < K; ++j) {
#pragma unroll
        for (int tf = 0; tf < TF; ++tf) {
            const int tl = wtt * (TT / 2) + tf * 16 + l15;
            const int xl = 2 * tl + j;
            const int xh = xl >> 1, p = xl & 1;
            xoff[j][tf] = xh * 128 + ((p * 64 + l16 * 16) ^ ((xh & 7) << 4));
        }
#pragma unroll
        for (int cf = 0; cf < 4; ++cf)
            woff[j][cf] = ((wco * 64 + cf * 16 + l15) * WROW + j * 32 + l16 * 8) * 2;
    }

    f32x4 acc[4][TF] = {};

    // prologue: X(0)->buf0, X(1)->buf1, W(0); drain; barrier
    stageX(xsA, &Xs[0][0]);
    stageX(xsB, &Xs[1][0]);
    stageW();
    __syncthreads();

    auto body = [&](int cit, u16* xb, const char* (&xset)[NIX]) {
        bf16x8 xr[K][TF], wr[K][4];
#pragma unroll
        for (int j = 0; j < K; ++j) {
#pragma unroll
            for (int tf = 0; tf < TF; ++tf)
                xr[j][tf] = *(const bf16x8*)((const char*)xb + xoff[j][tf]);
#pragma unroll
            for (int cf = 0; cf < 4; ++cf)
                wr[j][cf] = *(const bf16x8*)((const char*)&Ws[0] + woff[j][cf]);
        }
        // MFMA taps 0..K-2: compiler interleaves its own counted lgkm waits,
        // hiding ds_read latency under the matrix pipe.
#pragma unroll
        for (int j = 0; j < K - 1; ++j)
#pragma unroll
            for (int cf = 0; cf < 4; ++cf)
#pragma unroll
                for (int tf = 0; tf < TF; ++tf)
                    acc[cf][tf] = __builtin_amdgcn_mfma_f32_16x16x32_bf16(
                        wr[j][cf], xr[j][tf], acc[cf][tf], 0, 0, 0);
        asm volatile("s_waitcnt lgkmcnt(0)" ::: "memory");   // all reads done
        __builtin_amdgcn_s_barrier();                        // buffers free
        if (cit < 15) stageW();                              // W(cit+1)
        if (cit < 14) stageX(xset, xb);                      // X(cit+2)
        // last tap covers the staging issue (regs already captured)
        {
            constexpr int j = K - 1;
#pragma unroll
            for (int cf = 0; cf < 4; ++cf)
#pragma unroll
                for (int tf = 0; tf < TF; ++tf)
                    acc[cf][tf] = __builtin_amdgcn_mfma_f32_16x16x32_bf16(
                        wr[j][cf], xr[j][tf], acc[cf][tf], 0, 0, 0);
        }
        if (cit < 14) {
            __builtin_amdgcn_s_waitcnt(vmimm(NIX));  // W(c+1),X(c+1) landed
            __builtin_amdgcn_s_barrier();
        } else if (cit == 14) {
            __builtin_amdgcn_s_waitcnt(vmimm(0));
            __builtin_amdgcn_s_barrier();
        }
    };

#pragma unroll 1
    for (int c2 = 0; c2 < 16; c2 += 2) {
        body(c2,     &Xs[0][0], xsA);
        body(c2 + 1, &Xs[1][0], xsB);
    }

    // epilogue: gelu + bf16 transposed store [b][t][512]
    u16* ob = outAct + (size_t)b * capOut * 512;
#pragma unroll
    for (int cf = 0; cf < 4; ++cf) {
#pragma unroll
        for (int tf = 0; tf < TF; ++tf) {
            const int tG  = t0 + wtt * (TT / 2) + tf * 16 + l15;
            const int coG = cob * 128 + wco * 64 + cf * 16 + l16 * 4;
            union { u16 s[4]; uint2 v; } pk;
#pragma unroll
            for (int r = 0; r < 4; ++r)
                pk.s[r] = f2bf(gelu_tanh(acc[cf][tf][r]));
            *(uint2*)(ob + (size_t)tG * 512 + coG) = pk.v;
        }
    }
}

// ---------------- time-mean + proj + relu ----------------------------------
__global__ __launch_bounds__(512) void feat_proj_kernel(
    const u16* __restrict__ act, int cap,
    const float* __restrict__ pw, const float* __restrict__ pb,
    float* __restrict__ pfeat) {
    const int b = blockIdx.x;
    __shared__ float fs[8][512];
    __shared__ float feat[CC];
    const int c8 = (threadIdx.x & 63) * 8;
    const int tg = threadIdx.x >> 6;
    float s[8] = {};
    for (int t = tg; t < 124; t += 8) {
        union { u16 u[8]; uint4 v; } in;
        in.v = *(const uint4*)(act + ((size_t)b * cap + t) * 512 + c8);
#pragma unroll
        for (int e = 0; e < 8; ++e) s[e] += bf2f(in.u[e]);
    }
#pragma unroll
    for (int e = 0; e < 8; ++e) fs[tg][c8 + e] = s[e];
    __syncthreads();
    {
        const int c = threadIdx.x;
        if (c < 512) {
            float acc = 0.0f;
#pragma unroll
            for (int g = 0; g < 8; ++g) acc += fs[g][c];
            feat[c] = acc * (1.0f / 124.0f);
        }
    }
    __syncthreads();
    if (threadIdx.x < 256) {
        const int j = threadIdx.x;
        const float* wr = pw + (size_t)j * CC;
        float acc = pb[j];
        for (int cc = 0; cc < CC; ++cc) acc = fmaf(feat[cc], wr[cc], acc);
        pfeat[b * 256 + j] = fmaxf(acc, 0.0f);
    }
}

// ---------------- per-sample classifier MLP --------------------------------
__global__ __launch_bounds__(128) void cls_kernel(
    const float* __restrict__ pfeat, const int* __restrict__ wid,
    const float* __restrict__ w1, const float* __restrict__ b1,
    const float* __restrict__ w2, const float* __restrict__ b2,
    float* __restrict__ out) {
    const int b = blockIdx.x;
    const int id = wid[b];
    __shared__ float pf[256], h1[128];
    for (int d = threadIdx.x; d < 256; d += 128) pf[d] = pfeat[b * 256 + d];
    __syncthreads();
    {
        const int hh = threadIdx.x;
        const float* w1p = w1 + (size_t)id * 256 * 128;
        float s = b1[id * 128 + hh];
        for (int d = 0; d < 256; ++d) s = fmaf(pf[d], w1p[d * 128 + hh], s);
        h1[hh] = fmaxf(s, 0.0f);
    }
    __syncthreads();
    if (threadIdx.x < 5) {
        const float* w2p = w2 + (size_t)id * 128 * 5;
        float s = b2[id * 5 + threadIdx.x];
        for (int hh = 0; hh < 128; ++hh) s = fmaf(h1[hh], w2p[hh * 5 + threadIdx.x], s);
        out[b * 5 + threadIdx.x] = s;
    }
}

// ---------------------------------------------------------------------------
extern "C" void kernel_launch(void* const* d_in, const int* in_sizes, int n_in,
                              void* d_out, int out_size, void* d_ws, size_t ws_size,
                              hipStream_t stream) {
    const float* x   = (const float*)d_in[0];
    const int*   wid = (const int*)d_in[1];
    const float* gsc = (const float*)d_in[2];
    const float* gbi = (const float*)d_in[3];
    const float* pw  = (const float*)d_in[4];
    const float* pb  = (const float*)d_in[5];
    const float* w1  = (const float*)d_in[6];
    const float* b1  = (const float*)d_in[7];
    const float* w2  = (const float*)d_in[8];
    const float* b2  = (const float*)d_in[9];
    const float* cw[7];
    for (int i = 0; i < 7; ++i) cw[i] = (const float*)d_in[10 + i];

    // ---- workspace layout ----
    char* ws = (char*)d_ws;
    const size_t SZ_ACTG = (size_t)8 * 8320 * 512 * 2;
    const size_t SZ_P    = (size_t)8 * 4224 * 512 * 2;
    const size_t SZ_Q    = (size_t)8 * 2176 * 512 * 2;
    u16* actG = (u16*)ws;
    u16* bufP = (u16*)(ws + SZ_ACTG);
    u16* bufQ = (u16*)(ws + SZ_ACTG + SZ_P);
    size_t off = SZ_ACTG + SZ_P + SZ_Q;
    u16* wtbuf[7];
    for (int i = 1; i <= 4; ++i) { wtbuf[i] = (u16*)(ws + off); off += (size_t)4 * 16 * 128 * 104 * 2; }
    for (int i = 5; i <= 6; ++i) { wtbuf[i] = (u16*)(ws + off); off += (size_t)4 * 16 * 128 * 72 * 2; }
    off = (off + 255) & ~(size_t)255;
    float* statsPart = (float*)(ws + off); off += (size_t)125 * 8 * 512 * 2 * 4;
    float* Af        = (float*)(ws + off); off += 4096 * 4;
    float* Bf        = (float*)(ws + off); off += 4096 * 4;
    float* pfeat     = (float*)(ws + off); off += 8 * 256 * 4;

    // ---- conv0: stats pass (no store) -> affine -> recompute+norm+store ---
    conv0_stats<<<dim3(125, 8), 256, 0, stream>>>(x, cw[0], statsPart);
    stats_finalizeAB<<<dim3(64), 256, 0, stream>>>(statsPart, gsc, gbi, Af, Bf);
    conv0_norm<<<dim3(125, 8), 256, 0, stream>>>(x, cw[0], Af, Bf, actG);

    // ---- weight pre-transforms (2 launches) ----
    {
        WtBatch<3, 4> a;
        for (int i = 0; i < 4; ++i) { a.src[i] = cw[1 + i]; a.dst[i] = wtbuf[1 + i]; }
        wt_transform<3, 4><<<dim3(16, 4, 4), 256, 0, stream>>>(a);
        WtBatch<2, 2> c;
        for (int i = 0; i < 2; ++i) { c.src[i] = cw[5 + i]; c.dst[i] = wtbuf[5 + i]; }
        wt_transform<2, 2><<<dim3(16, 4, 2), 256, 0, stream>>>(c);
    }

    // ---- conv chain: 1-D grids, blocks = nTb*4*8, tbShift = log2(nTb) ----
    conv_mfma<3, 128><<<dim3(32 * 32), 256, 0, stream>>>(actG, 8320, wtbuf[1], bufP, 4224, 5);
    conv_mfma<3, 128><<<dim3(16 * 32), 256, 0, stream>>>(bufP, 4224, wtbuf[2], bufQ, 2176, 4);
    conv_mfma<3,  64><<<dim3(16 * 32), 256, 0, stream>>>(bufQ, 2176, wtbuf[3], bufP, 4224, 4);
    conv_mfma<3,  64><<<dim3( 8 * 32), 256, 0, stream>>>(bufP, 4224, wtbuf[4], bufQ, 2176, 3);
    conv_mfma<2,  64><<<dim3( 4 * 32), 256, 0, stream>>>(bufQ, 2176, wtbuf[5], bufP, 4224, 2);
    conv_mfma<2,  64><<<dim3( 2 * 32), 256, 0, stream>>>(bufP, 4224, wtbuf[6], bufQ, 2176, 1);

    // ---- tail ----
    feat_proj_kernel<<<dim3(8), 512, 0, stream>>>(bufQ, 2176, pw, pb, pfeat);
    cls_kernel<<<dim3(8), 128, 0, stream>>>(pfeat, wid, w1, b1, w2, b2, (float*)d_out);
}

// Round 17
// 283.790 us; speedup vs baseline: 1.3192x; 1.0953x over previous
//
#include <hip/hip_runtime.h>
#include <hip/hip_bf16.h>

typedef unsigned short u16;
typedef short bf16x8 __attribute__((ext_vector_type(8)));
typedef float f32x4 __attribute__((ext_vector_type(4)));

#define CC 512

// s_waitcnt imm encoding: vmcnt[3:0]|[15:14], expcnt[6:4]=7 (no wait),
// lgkmcnt[11:8]=0xF (no wait)
constexpr int vmimm(int n) {
    return (n & 0xF) | ((n >> 4) << 14) | (0x7 << 4) | (0xF << 8);
}

__device__ __forceinline__ float gelu_tanh(float x) {
    float x3 = x * x * x;
    float z  = 0.7978845608028654f * (x + 0.044715f * x3);
    float e  = __expf(2.0f * z);
    float th = 1.0f - 2.0f / (e + 1.0f);
    return 0.5f * x * (1.0f + th);
}

__device__ __forceinline__ u16 f2bf(float f) {
    union { float f; unsigned u; } v; v.f = f;
    unsigned r = v.u + 0x7fff + ((v.u >> 16) & 1);
    return (u16)(r >> 16);
}
__device__ __forceinline__ float bf2f(u16 h) {
    union { unsigned u; float f; } v; v.u = ((unsigned)h) << 16; return v.f;
}

// ---------------- conv0 pass 1: per-channel partial stats (NO store) -------
__global__ __launch_bounds__(256) void conv0_stats(
    const float* __restrict__ x, const float* __restrict__ w0,
    float* __restrict__ part) {
    const int t0 = blockIdx.x * 64, b = blockIdx.y;
    __shared__ float xs[64 * 5 + 16];
    __shared__ float w0t[10 * 512];
    __shared__ float redS[4][512], redQ[4][512];
    for (int i = threadIdx.x; i < 64 * 5 + 5; i += 256) {
        int gi = t0 * 5 + i;
        xs[i] = (gi < 40000) ? x[b * 40000 + gi] : 0.0f;
    }
    for (int i = threadIdx.x; i < 5120; i += 256) {
        int c = i / 10, j = i - c * 10;
        w0t[j * 512 + c] = w0[i];
    }
    __syncthreads();
    const int lane = threadIdx.x & 63, wv = threadIdx.x >> 6;
    float wr[8][10];
#pragma unroll
    for (int q = 0; q < 8; ++q)
#pragma unroll
        for (int j = 0; j < 10; ++j) wr[q][j] = w0t[j * 512 + lane + 64 * q];
    float sacc[8] = {}, qacc[8] = {};
#pragma unroll
    for (int u = 0; u < 16; ++u) {
        const int tt = wv * 16 + u;
        const int t  = t0 + tt;
        float xv[10];
#pragma unroll
        for (int j = 0; j < 10; ++j) xv[j] = xs[tt * 5 + j];
#pragma unroll
        for (int q = 0; q < 8; ++q) {
            float a = 0.0f;
#pragma unroll
            for (int j = 0; j < 10; ++j) a = fmaf(wr[q][j], xv[j], a);
            if (t < 7999) {
                const float ar = bf2f(f2bf(a));
                sacc[q] += ar; qacc[q] += ar * ar;
            }
        }
    }
#pragma unroll
    for (int q = 0; q < 8; ++q) {
        redS[wv][lane + 64 * q] = sacc[q];
        redQ[wv][lane + 64 * q] = qacc[q];
    }
    __syncthreads();
    float* pp = part + (((size_t)blockIdx.x * 8 + b) * 512) * 2;
#pragma unroll
    for (int half = 0; half < 2; ++half) {
        const int c = half * 256 + threadIdx.x;
        const float s = redS[0][c] + redS[1][c] + redS[2][c] + redS[3][c];
        const float q = redQ[0][c] + redQ[1][c] + redQ[2][c] + redQ[3][c];
        pp[c * 2] = s; pp[c * 2 + 1] = q;
    }
}

// reduce partials (125 per row) -> per-(b,c) affine A,B
__global__ __launch_bounds__(256) void stats_finalizeAB(
    const float* __restrict__ part, const float* __restrict__ gsc,
    const float* __restrict__ gbi, float* __restrict__ Af, float* __restrict__ Bf) {
    const int r4 = threadIdx.x & 63, kg = threadIdx.x >> 6;
    const int row = blockIdx.x * 64 + r4;            // b*512 + c
    float s = 0.0f, q = 0.0f;
    for (int k = kg; k < 125; k += 4) {
        const float2 v = *(const float2*)(part + ((size_t)k * 4096 + row) * 2);
        s += v.x; q += v.y;
    }
    __shared__ float rs[4][64], rq[4][64];
    rs[kg][r4] = s; rq[kg][r4] = q;
    __syncthreads();
    if (kg == 0) {
        s = rs[0][r4] + rs[1][r4] + rs[2][r4] + rs[3][r4];
        q = rq[0][r4] + rq[1][r4] + rq[2][r4] + rq[3][r4];
        float mean = s / 7999.0f;
        float var  = fmaxf(q / 7999.0f - mean * mean, 0.0f);
        float rstd = rsqrtf(var + 1e-5f);
        const int c = row & (CC - 1);
        float A = rstd * gsc[c];
        Af[row] = A;
        Bf[row] = gbi[c] - mean * A;
    }
}

// ---------------- conv0 pass 2: recompute + norm + gelu -> actG ------------
__global__ __launch_bounds__(256) void conv0_norm(
    const float* __restrict__ x, const float* __restrict__ w0,
    const float* __restrict__ Af, const float* __restrict__ Bf,
    u16* __restrict__ actG) {
    const int t0 = blockIdx.x * 64, b = blockIdx.y;
    __shared__ float xs[64 * 5 + 16];
    __shared__ float w0t[10 * 512];
    for (int i = threadIdx.x; i < 64 * 5 + 5; i += 256) {
        int gi = t0 * 5 + i;
        xs[i] = (gi < 40000) ? x[b * 40000 + gi] : 0.0f;
    }
    for (int i = threadIdx.x; i < 5120; i += 256) {
        int c = i / 10, j = i - c * 10;
        w0t[j * 512 + c] = w0[i];
    }
    __syncthreads();
    const int lane = threadIdx.x & 63, wv = threadIdx.x >> 6;
    float wr[8][10];
    float Ar[8], Br[8];
#pragma unroll
    for (int q = 0; q < 8; ++q) {
        const int c = lane + 64 * q;
#pragma unroll
        for (int j = 0; j < 10; ++j) wr[q][j] = w0t[j * 512 + c];
        Ar[q] = Af[b * 512 + c];
        Br[q] = Bf[b * 512 + c];
    }
    u16* ob = actG + ((size_t)b * 8320 + t0 + wv * 16) * 512 + lane;
#pragma unroll
    for (int u = 0; u < 16; ++u) {
        const int tt = wv * 16 + u;
        const int t  = t0 + tt;
        float xv[10];
#pragma unroll
        for (int j = 0; j < 10; ++j) xv[j] = xs[tt * 5 + j];
#pragma unroll
        for (int q = 0; q < 8; ++q) {
            float a = 0.0f;
#pragma unroll
            for (int j = 0; j < 10; ++j) a = fmaf(wr[q][j], xv[j], a);
            u16 outv = 0;
            if (t < 7999) {
                const float ar = bf2f(f2bf(a));
                outv = f2bf(gelu_tanh(fmaf(ar, Ar[q], Br[q])));
            }
            ob[(size_t)u * 512 + 64 * q] = outv;
        }
    }
}

// ---------------- weight pre-transform: FRAGMENT-ORDER layout --------------
// Per (cob,cit): plane of K*8 regions x 1024 B. Region r = cf*K + j
// (cf = co-16-block 0..7, j = tap). Lane l's 16 B at r*1024 + l*16 hold
// W[co = cob*128+cf*16+(l&15)][ci = cit*32+(l>>4)*8+e][j], e=0..7 -- the
// exact mfma_16x16x32 A-fragment. LDS reads become fully linear (0-conflict)
// and staging is a pure linear copy with exact instr counts.
template <int K, int NL>
struct WtBatch { const float* src[NL]; u16* dst[NL]; };

template <int K, int NL>
__global__ __launch_bounds__(256) void wt_transform(WtBatch<K, NL> a) {
    constexpr int PLANE_U16 = K * 4096;     // K*8 regions * 512 u16
    const int cit = blockIdx.x, cob = blockIdx.y, l = blockIdx.z;
    const float* w = a.src[l];
    u16* dst = a.dst[l] + ((size_t)(cob * 16 + cit)) * PLANE_U16;
    for (int idx = threadIdx.x; idx < PLANE_U16; idx += 256) {
        const int r  = idx >> 9;            // region = cf*K + j
        const int cf = r / K, j = r - cf * K;
        const int li = (idx >> 3) & 63;     // lane
        const int e  = idx & 7;
        const int co = cob * 128 + cf * 16 + (li & 15);
        const int ci = cit * 32 + ((li >> 4) << 3) + e;
        dst[idx] = f2bf(w[((size_t)co * 512 + ci) * K + j]);
    }
}

// ---------------- MFMA conv (512->512, k=K, stride 2) + gelu ---------------
// Block 128co x TT t, 4 waves (2co x 2t). Depth-2 counted-vmcnt pipeline:
// X double-buffered in LDS, W single-buffered (fragment-order layout).
// Per cit: ds_read frags -> lgkm(0) -> s_barrier -> stage W(cit+1), X(cit+2)
//   -> MFMA (covers latency) -> vmcnt(NIX) -> s_barrier.
// Per-wave staging: contiguous chunk ranges; W counts exact (NIW = 2K), X
// lane-masked last load -> every wave issues EXACTLY NIW/NIX loads, so
// vmcnt(N) is exact; W issued before X -> remaining after wait = NIX.
// VGPR NOTE: never cap below ~130 via launch_bounds (R6/R10 spill disasters).
template <int K, int TT>
__global__ __launch_bounds__(256, 2) void conv_mfma(
    const u16* __restrict__ act, int capIn,
    const u16* __restrict__ wt,
    u16* __restrict__ outAct, int capOut, int tbShift) {
    constexpr int PLANE_B = K * 8192;        // W plane bytes
    constexpr int XH   = TT + 8;             // x-pair rows (128 B each)
    constexpr int TF   = TT / 32;
    constexpr int TXC  = XH * 8;             // 16B chunks per X buffer
    constexpr int CPX  = TXC / 4;            // chunks per wave
    constexpr int NIX  = (CPX + 63) / 64;    // X stage instrs per wave
    constexpr int XLAST = CPX - (NIX - 1) * 64;
    constexpr int CPW  = K * 128;            // W chunks per wave (exact)
    constexpr int NIW  = K * 2;              // W stage instrs per wave

    __shared__ __align__(16) u16 Xs[2][XH * 64];
    __shared__ __align__(16) u16 Ws[K * 4096];

    const int tid  = threadIdx.x;
    const int lane = tid & 63;
    const int wv   = tid >> 6;
    const int wco  = wv >> 1, wtt = wv & 1;
    const int l15  = lane & 15, l16 = lane >> 4;

    const int flat = blockIdx.x;
    const int xcd  = flat & 7, cob = (flat >> 3) & 3;
    const int G    = xcd + (flat >> 5) * 8;
    const int t_b  = G & ((1 << tbShift) - 1);
    const int b    = G >> tbShift;
    const int t0   = t_b * TT;
    const int x0   = t0 * 2;

    const char* abase = (const char*)(act + (size_t)b * capIn * 512);
    const char* wbase = (const char*)wt + (size_t)cob * (16 * PLANE_B);

    // ---- staging pointers: set A stages even cits (buf0), B odd (buf1) ----
    const char* xsA[NIX]; const char* xsB[NIX]; int xdst[NIX];
#pragma unroll
    for (int i = 0; i < NIX; ++i) {
        const int c  = wv * CPX + i * 64 + lane;
        const int xh = c >> 3;
        const int li = ((c & 7) * 16) ^ ((xh & 7) << 4);
        const int xx = min(x0 + 2 * xh + (li >> 6), capIn - 1);
        xsA[i] = abase + (size_t)xx * 1024 + (li & 63);
        xsB[i] = xsA[i] + 64;                       // +1 cit
        xdst[i] = (wv * CPX + i * 64) * 16;         // wave-uniform LDS base
    }
    const char* wsrc[NIW]; int wdst[NIW];
#pragma unroll
    for (int i = 0; i < NIW; ++i) {
        wsrc[i] = wbase + (size_t)(wv * CPW + i * 64 + lane) * 16;
        wdst[i] = (wv * CPW + i * 64) * 16;
    }

    auto stageX = [&](const char* (&xs)[NIX], u16* xb) {
#pragma unroll
        for (int i = 0; i < NIX; ++i)
            if (i < NIX - 1 || lane < XLAST)
                __builtin_amdgcn_global_load_lds(
                    (const __attribute__((address_space(1))) void*)xs[i],
                    (__attribute__((address_space(3))) void*)((char*)xb + xdst[i]),
                    16, 0, 0);
#pragma unroll
        for (int i = 0; i < NIX; ++i) xs[i] += 128;          // +2 cits
    };
    auto stageW = [&]() {
#pragma unroll
        for (int i = 0; i < NIW; ++i)
            __builtin_amdgcn_global_load_lds(
                (const __attribute__((address_space(1))) void*)wsrc[i],
                (__attribute__((address_space(3))) void*)((char*)&Ws[0] + wdst[i]),
                16, 0, 0);
#pragma unroll
        for (int i = 0; i < NIW; ++i) wsrc[i] += PLANE_B;    // next cit plane
    };

    // cit-invariant fragment offsets (bytes)
    int xoff[K][TF];
    int woff[K][4];
#pragma unroll
    for (int j = 0; j < K; ++j) {
#pragma unroll
        for (int tf = 0; tf < TF; ++tf) {
            const int tl = wtt * (TT / 2) + tf * 16 + l15;
            const int xl = 2 * tl + j;
            const int xh = xl >> 1, p = xl & 1;
            xoff[j][tf] = xh * 128 + ((p * 64 + l16 * 16) ^ ((xh & 7) << 4));
        }
#pragma unroll
        for (int cf = 0; cf < 4; ++cf)
            woff[j][cf] = (((wco * 4 + cf) * K + j) << 10) + lane * 16;
    }

    f32x4 acc[4][TF] = {};

    // prologue: X(0)->buf0, X(1)->buf1, W(0); drain; barrier
    stageX(xsA, &Xs[0][0]);
    stageX(xsB, &Xs[1][0]);
    stageW();
    __syncthreads();

    auto body = [&](int cit, u16* xb, const char* (&xset)[NIX]) {
        bf16x8 xr[K][TF], wr[K][4];
#pragma unroll
        for (int j = 0; j < K; ++j) {
#pragma unroll
            for (int tf = 0; tf < TF; ++tf)
                xr[j][tf] = *(const bf16x8*)((const char*)xb + xoff[j][tf]);
#pragma unroll
            for (int cf = 0; cf < 4; ++cf)
                wr[j][cf] = *(const bf16x8*)((const char*)&Ws[0] + woff[j][cf]);
        }
        asm volatile("s_waitcnt lgkmcnt(0)" ::: "memory");   // reads complete
        __builtin_amdgcn_s_barrier();                        // all waves done
        if (cit < 15) stageW();                              // W(cit+1)
        if (cit < 14) stageX(xset, xb);                      // X(cit+2)
#pragma unroll
        for (int j = 0; j < K; ++j)
#pragma unroll
            for (int cf = 0; cf < 4; ++cf)
#pragma unroll
                for (int tf = 0; tf < TF; ++tf)
                    acc[cf][tf] = __builtin_amdgcn_mfma_f32_16x16x32_bf16(
                        wr[j][cf], xr[j][tf], acc[cf][tf], 0, 0, 0);
        if (cit < 14) {
            __builtin_amdgcn_s_waitcnt(vmimm(NIX));  // W(c+1),X(c+1) landed
            __builtin_amdgcn_s_barrier();
        } else if (cit == 14) {
            __builtin_amdgcn_s_waitcnt(vmimm(0));
            __builtin_amdgcn_s_barrier();
        }
    };

#pragma unroll 1
    for (int c2 = 0; c2 < 16; c2 += 2) {
        body(c2,     &Xs[0][0], xsA);
        body(c2 + 1, &Xs[1][0], xsB);
    }

    // epilogue: gelu + bf16 transposed store [b][t][512]
    u16* ob = outAct + (size_t)b * capOut * 512;
#pragma unroll
    for (int cf = 0; cf < 4; ++cf) {
#pragma unroll
        for (int tf = 0; tf < TF; ++tf) {
            const int tG  = t0 + wtt * (TT / 2) + tf * 16 + l15;
            const int coG = cob * 128 + wco * 64 + cf * 16 + l16 * 4;
            union { u16 s[4]; uint2 v; } pk;
#pragma unroll
            for (int r = 0; r < 4; ++r)
                pk.s[r] = f2bf(gelu_tanh(acc[cf][tf][r]));
            *(uint2*)(ob + (size_t)tG * 512 + coG) = pk.v;
        }
    }
}

// ---------------- time-mean + proj + relu ----------------------------------
__global__ __launch_bounds__(512) void feat_proj_kernel(
    const u16* __restrict__ act, int cap,
    const float* __restrict__ pw, const float* __restrict__ pb,
    float* __restrict__ pfeat) {
    const int b = blockIdx.x;
    __shared__ float fs[8][512];
    __shared__ float feat[CC];
    const int c8 = (threadIdx.x & 63) * 8;
    const int tg = threadIdx.x >> 6;
    float s[8] = {};
    for (int t = tg; t < 124; t += 8) {
        union { u16 u[8]; uint4 v; } in;
        in.v = *(const uint4*)(act + ((size_t)b * cap + t) * 512 + c8);
#pragma unroll
        for (int e = 0; e < 8; ++e) s[e] += bf2f(in.u[e]);
    }
#pragma unroll
    for (int e = 0; e < 8; ++e) fs[tg][c8 + e] = s[e];
    __syncthreads();
    {
        const int c = threadIdx.x;
        if (c < 512) {
            float acc = 0.0f;
#pragma unroll
            for (int g = 0; g < 8; ++g) acc += fs[g][c];
            feat[c] = acc * (1.0f / 124.0f);
        }
    }
    __syncthreads();
    if (threadIdx.x < 256) {
        const int j = threadIdx.x;
        const float* wr = pw + (size_t)j * CC;
        float acc = pb[j];
        for (int cc = 0; cc < CC; ++cc) acc = fmaf(feat[cc], wr[cc], acc);
        pfeat[b * 256 + j] = fmaxf(acc, 0.0f);
    }
}

// ---------------- per-sample classifier MLP --------------------------------
__global__ __launch_bounds__(128) void cls_kernel(
    const float* __restrict__ pfeat, const int* __restrict__ wid,
    const float* __restrict__ w1, const float* __restrict__ b1,
    const float* __restrict__ w2, const float* __restrict__ b2,
    float* __restrict__ out) {
    const int b = blockIdx.x;
    const int id = wid[b];
    __shared__ float pf[256], h1[128];
    for (int d = threadIdx.x; d < 256; d += 128) pf[d] = pfeat[b * 256 + d];
    __syncthreads();
    {
        const int hh = threadIdx.x;
        const float* w1p = w1 + (size_t)id * 256 * 128;
        float s = b1[id * 128 + hh];
        for (int d = 0; d < 256; ++d) s = fmaf(pf[d], w1p[d * 128 + hh], s);
        h1[hh] = fmaxf(s, 0.0f);
    }
    __syncthreads();
    if (threadIdx.x < 5) {
        const float* w2p = w2 + (size_t)id * 128 * 5;
        float s = b2[id * 5 + threadIdx.x];
        for (int hh = 0; hh < 128; ++hh) s = fmaf(h1[hh], w2p[hh * 5 + threadIdx.x], s);
        out[b * 5 + threadIdx.x] = s;
    }
}

// ---------------------------------------------------------------------------
extern "C" void kernel_launch(void* const* d_in, const int* in_sizes, int n_in,
                              void* d_out, int out_size, void* d_ws, size_t ws_size,
                              hipStream_t stream) {
    const float* x   = (const float*)d_in[0];
    const int*   wid = (const int*)d_in[1];
    const float* gsc = (const float*)d_in[2];
    const float* gbi = (const float*)d_in[3];
    const float* pw  = (const float*)d_in[4];
    const float* pb  = (const float*)d_in[5];
    const float* w1  = (const float*)d_in[6];
    const float* b1  = (const float*)d_in[7];
    const float* w2  = (const float*)d_in[8];
    const float* b2  = (const float*)d_in[9];
    const float* cw[7];
    for (int i = 0; i < 7; ++i) cw[i] = (const float*)d_in[10 + i];

    // ---- workspace layout ----
    char* ws = (char*)d_ws;
    const size_t SZ_ACTG = (size_t)8 * 8320 * 512 * 2;
    const size_t SZ_P    = (size_t)8 * 4224 * 512 * 2;
    const size_t SZ_Q    = (size_t)8 * 2176 * 512 * 2;
    u16* actG = (u16*)ws;
    u16* bufP = (u16*)(ws + SZ_ACTG);
    u16* bufQ = (u16*)(ws + SZ_ACTG + SZ_P);
    size_t off = SZ_ACTG + SZ_P + SZ_Q;
    u16* wtbuf[7];
    for (int i = 1; i <= 4; ++i) { wtbuf[i] = (u16*)(ws + off); off += (size_t)4 * 16 * (3 * 4096) * 2; }
    for (int i = 5; i <= 6; ++i) { wtbuf[i] = (u16*)(ws + off); off += (size_t)4 * 16 * (2 * 4096) * 2; }
    off = (off + 255) & ~(size_t)255;
    float* statsPart = (float*)(ws + off); off += (size_t)125 * 8 * 512 * 2 * 4;
    float* Af        = (float*)(ws + off); off += 4096 * 4;
    float* Bf        = (float*)(ws + off); off += 4096 * 4;
    float* pfeat     = (float*)(ws + off); off += 8 * 256 * 4;

    // ---- conv0: stats pass (no store) -> affine -> recompute+norm+store ---
    conv0_stats<<<dim3(125, 8), 256, 0, stream>>>(x, cw[0], statsPart);
    stats_finalizeAB<<<dim3(64), 256, 0, stream>>>(statsPart, gsc, gbi, Af, Bf);
    conv0_norm<<<dim3(125, 8), 256, 0, stream>>>(x, cw[0], Af, Bf, actG);

    // ---- weight pre-transforms (2 launches) ----
    {
        WtBatch<3, 4> a;
        for (int i = 0; i < 4; ++i) { a.src[i] = cw[1 + i]; a.dst[i] = wtbuf[1 + i]; }
        wt_transform<3, 4><<<dim3(16, 4, 4), 256, 0, stream>>>(a);
        WtBatch<2, 2> c;
        for (int i = 0; i < 2; ++i) { c.src[i] = cw[5 + i]; c.dst[i] = wtbuf[5 + i]; }
        wt_transform<2, 2><<<dim3(16, 4, 2), 256, 0, stream>>>(c);
    }

    // ---- conv chain: 1-D grids, blocks = nTb*4*8, tbShift = log2(nTb) ----
    conv_mfma<3, 128><<<dim3(32 * 32), 256, 0, stream>>>(actG, 8320, wtbuf[1], bufP, 4224, 5);
    conv_mfma<3, 128><<<dim3(16 * 32), 256, 0, stream>>>(bufP, 4224, wtbuf[2], bufQ, 2176, 4);
    conv_mfma<3,  64><<<dim3(16 * 32), 256, 0, stream>>>(bufQ, 2176, wtbuf[3], bufP, 4224, 4);
    conv_mfma<3,  64><<<dim3( 8 * 32), 256, 0, stream>>>(bufP, 4224, wtbuf[4], bufQ, 2176, 3);
    conv_mfma<2,  64><<<dim3( 4 * 32), 256, 0, stream>>>(bufQ, 2176, wtbuf[5], bufP, 4224, 2);
    conv_mfma<2,  64><<<dim3( 2 * 32), 256, 0, stream>>>(bufP, 4224, wtbuf[6], bufQ, 2176, 1);

    // ---- tail ----
    feat_proj_kernel<<<dim3(8), 512, 0, stream>>>(bufQ, 2176, pw, pb, pfeat);
    cls_kernel<<<dim3(8), 128, 0, stream>>>(pfeat, wid, w1, b1, w2, b2, (float*)d_out);
}